// Round 3
// baseline (8476.627 us; speedup 1.0000x reference)
//
#include <hip/hip_runtime.h>
#include <math.h>

// RWKV6 block forward, fp32, ws_size-adaptive batch chunking.
// B=8 T=2048 C=1024 H=16 N=64 F=3584.
// Footprint per chunk of Bc sequences: Bc*Tn*(6*Cn+224)*4 bytes ~= Bc*49.8 MiB.

#define DEVI static __device__ __forceinline__

constexpr int Tn = 2048, Cn = 1024, Hn = 16, Nn = 64;
constexpr int Bn = 8;
constexpr size_t BTC = (size_t)Bn * Tn * Cn;

enum { EPI_NONE = 0, EPI_TANH, EPI_SILU, EPI_SIGMOID, EPI_RELU2,
       EPI_DECAY, EPI_RESID, EPI_MULADD, EPI_MIX };

// ---------------- reductions ----------------
DEVI float wave_sum(float v) {
  v += __shfl_xor(v, 32); v += __shfl_xor(v, 16); v += __shfl_xor(v, 8);
  v += __shfl_xor(v, 4);  v += __shfl_xor(v, 2);  v += __shfl_xor(v, 1);
  return v;
}

DEVI float blk_sum(float v, float* sb) {
  v = wave_sum(v);
  int tid = threadIdx.x;
  if ((tid & 63) == 0) sb[tid >> 6] = v;
  __syncthreads();
  v = sb[0] + sb[1] + sb[2] + sb[3];
  __syncthreads();
  return v;
}

// ---------------- misc ----------------
__global__ __launch_bounds__(256) void zero_kernel(float* p, size_t n) {
  for (size_t i = (size_t)blockIdx.x * 256 + threadIdx.x; i < n;
       i += (size_t)gridDim.x * 256) p[i] = 0.f;
}

// ---------------- LayerNorm kernels ----------------
__global__ __launch_bounds__(256) void ln01_kernel(
    const float* __restrict__ x,
    const float* __restrict__ g0, const float* __restrict__ b0,
    const float* __restrict__ g1, const float* __restrict__ b1,
    float* __restrict__ x0, float* __restrict__ xa)
{
  __shared__ float sb[4];
  const int tid = threadIdx.x;
  const size_t base = (size_t)blockIdx.x * Cn + tid * 4;
  float4 v = *(const float4*)(x + base);
  float mean = blk_sum(v.x + v.y + v.z + v.w, sb) * (1.f / Cn);
  float4 d = make_float4(v.x - mean, v.y - mean, v.z - mean, v.w - mean);
  float var = blk_sum(d.x*d.x + d.y*d.y + d.z*d.z + d.w*d.w, sb) * (1.f / Cn);
  float rs = rsqrtf(var + 1e-5f);
  float4 gg = *(const float4*)(g0 + tid * 4), bb = *(const float4*)(b0 + tid * 4);
  float4 y = make_float4(d.x*rs*gg.x + bb.x, d.y*rs*gg.y + bb.y,
                         d.z*rs*gg.z + bb.z, d.w*rs*gg.w + bb.w);
  *(float4*)(x0 + base) = y;
  float mean2 = blk_sum(y.x + y.y + y.z + y.w, sb) * (1.f / Cn);
  float4 d2 = make_float4(y.x - mean2, y.y - mean2, y.z - mean2, y.w - mean2);
  float var2 = blk_sum(d2.x*d2.x + d2.y*d2.y + d2.z*d2.z + d2.w*d2.w, sb) * (1.f / Cn);
  float rs2 = rsqrtf(var2 + 1e-5f);
  gg = *(const float4*)(g1 + tid * 4); bb = *(const float4*)(b1 + tid * 4);
  *(float4*)(xa + base) = make_float4(d2.x*rs2*gg.x + bb.x, d2.y*rs2*gg.y + bb.y,
                                      d2.z*rs2*gg.z + bb.z, d2.w*rs2*gg.w + bb.w);
}

__global__ __launch_bounds__(256) void ln_kernel(
    const float* __restrict__ in, const float* __restrict__ g,
    const float* __restrict__ b, float* __restrict__ out)
{
  __shared__ float sb[4];
  const int tid = threadIdx.x;
  const size_t base = (size_t)blockIdx.x * Cn + tid * 4;
  float4 v = *(const float4*)(in + base);
  float mean = blk_sum(v.x + v.y + v.z + v.w, sb) * (1.f / Cn);
  float4 d = make_float4(v.x - mean, v.y - mean, v.z - mean, v.w - mean);
  float var = blk_sum(d.x*d.x + d.y*d.y + d.z*d.z + d.w*d.w, sb) * (1.f / Cn);
  float rs = rsqrtf(var + 1e-5f);
  float4 gg = *(const float4*)(g + tid * 4), bb = *(const float4*)(b + tid * 4);
  *(float4*)(out + base) = make_float4(d.x*rs*gg.x + bb.x, d.y*rs*gg.y + bb.y,
                                       d.z*rs*gg.z + bb.z, d.w*rs*gg.w + bb.w);
}

// per-head groupnorm (over N=64) * lnx affine * gate, in-place on o.
__global__ __launch_bounds__(256) void gn_kernel(
    float* o, const float* __restrict__ g, const float* __restrict__ b,
    const float* __restrict__ gate)
{
  const int tid = threadIdx.x;
  const int row = blockIdx.x * 4 + (tid >> 6);
  const int lane = tid & 63;
  const size_t idx = (size_t)row * Nn + lane;
  float val = o[idx];
  float mean = wave_sum(val) * (1.f / Nn);
  float d = val - mean;
  float var = wave_sum(d * d) * (1.f / Nn);
  float rs = rsqrtf(var + 1e-5f);
  int c = (row & (Hn - 1)) * Nn + lane;
  o[idx] = (d * rs * g[c] + b[c]) * gate[idx];
}

// token-shift mix: out = x + (shift(x)-x)*maa  (one or two outputs)
__global__ __launch_bounds__(256) void mixshift_kernel(
    const float* __restrict__ xin,
    const float* __restrict__ maaA, float* __restrict__ outA,
    const float* __restrict__ maaB, float* __restrict__ outB, size_t n4)
{
  const int C4 = Cn / 4;          // 256
  for (size_t i = (size_t)blockIdx.x * 256 + threadIdx.x; i < n4;
       i += (size_t)gridDim.x * 256) {
    int c4 = (int)(i & (C4 - 1));
    size_t bt = i >> 8;
    float4 cur = ((const float4*)xin)[i];
    float4 prev = make_float4(0.f, 0.f, 0.f, 0.f);
    if (bt % Tn) prev = ((const float4*)xin)[i - C4];
    float4 ma = ((const float4*)maaA)[c4];
    ((float4*)outA)[i] = make_float4(
        cur.x + (prev.x - cur.x) * ma.x, cur.y + (prev.y - cur.y) * ma.y,
        cur.z + (prev.z - cur.z) * ma.z, cur.w + (prev.w - cur.w) * ma.w);
    if (maaB) {
      float4 mb = ((const float4*)maaB)[c4];
      ((float4*)outB)[i] = make_float4(
          cur.x + (prev.x - cur.x) * mb.x, cur.y + (prev.y - cur.y) * mb.y,
          cur.z + (prev.z - cur.z) * mb.z, cur.w + (prev.w - cur.w) * mb.w);
    }
  }
}

// ---------------- generic fp32 GEMM ----------------
template<int EPI>
DEVI float epi_apply(float v, int row, int col, int Nc,
                     const float* e1, const float* e2)
{
  if constexpr (EPI == EPI_NONE) { return v; }
  else if constexpr (EPI == EPI_TANH) { return tanhf(v); }
  else if constexpr (EPI == EPI_SILU) { return v / (1.f + expf(-v)); }
  else if constexpr (EPI == EPI_SIGMOID) { return 1.f / (1.f + expf(-v)); }
  else if constexpr (EPI == EPI_RELU2) { float r = fmaxf(v, 0.f); return r * r; }
  else if constexpr (EPI == EPI_DECAY) { return expf(-expf(v + e1[col])); }
  else if constexpr (EPI == EPI_RESID) { return v + e1[(size_t)row * Nc + col]; }
  else if constexpr (EPI == EPI_MULADD) {
    size_t i = (size_t)row * Nc + col; return v * e1[i] + e2[i];
  } else { // EPI_MIX: out = xa + (shift(xa)-xa)*(maa + acc); e1=xa, e2=maa
    size_t i = (size_t)row * Nc + col;
    float cur = e1[i];
    float prev = (row % Tn) ? e1[i - Cn] : 0.f;
    return cur + (prev - cur) * (e2[col] + v);
  }
}

template<int EPI>
__global__ __launch_bounds__(256) void gemm_kernel(
    const float* __restrict__ A, int ldA,
    const float* __restrict__ W,          // K x Nc, row-major
    float* out, int Nc, int K,
    const float* e1, const float* e2)
{
  constexpr int BK = 16;
  __shared__ float As[BK][132];
  __shared__ float Bs[BK][128];
  const int tid = threadIdx.x;
  const int m0 = blockIdx.y * 128, n0 = blockIdx.x * 128;
  const int tx = tid & 15, ty = tid >> 4;
  const int am = tid >> 2, ak = (tid & 3) << 2;
  const int bn = (tid & 31) << 2, bk = tid >> 5;

  float acc[8][8];
  #pragma unroll
  for (int i = 0; i < 8; i++)
    #pragma unroll
    for (int j = 0; j < 8; j++) acc[i][j] = 0.f;

  for (int k0 = 0; k0 < K; k0 += BK) {
    float4 va = *(const float4*)(A + (size_t)(m0 + am) * ldA + k0 + ak);
    float4 vb = *(const float4*)(A + (size_t)(m0 + 64 + am) * ldA + k0 + ak);
    float4 w1 = make_float4(0.f, 0.f, 0.f, 0.f);
    float4 w2 = make_float4(0.f, 0.f, 0.f, 0.f);
    if (n0 + bn < Nc) {
      w1 = *(const float4*)(W + (size_t)(k0 + bk) * Nc + n0 + bn);
      w2 = *(const float4*)(W + (size_t)(k0 + bk + 8) * Nc + n0 + bn);
    }
    As[ak + 0][am] = va.x; As[ak + 1][am] = va.y;
    As[ak + 2][am] = va.z; As[ak + 3][am] = va.w;
    As[ak + 0][64 + am] = vb.x; As[ak + 1][64 + am] = vb.y;
    As[ak + 2][64 + am] = vb.z; As[ak + 3][64 + am] = vb.w;
    *(float4*)&Bs[bk][bn] = w1;
    *(float4*)&Bs[bk + 8][bn] = w2;
    __syncthreads();
    #pragma unroll
    for (int kk = 0; kk < BK; kk++) {
      float4 a0 = *(const float4*)&As[kk][ty * 8];
      float4 a1 = *(const float4*)&As[kk][ty * 8 + 4];
      float4 b0 = *(const float4*)&Bs[kk][tx * 8];
      float4 b1 = *(const float4*)&Bs[kk][tx * 8 + 4];
      float av[8] = {a0.x, a0.y, a0.z, a0.w, a1.x, a1.y, a1.z, a1.w};
      float bv[8] = {b0.x, b0.y, b0.z, b0.w, b1.x, b1.y, b1.z, b1.w};
      #pragma unroll
      for (int i = 0; i < 8; i++)
        #pragma unroll
        for (int j = 0; j < 8; j++)
          acc[i][j] = fmaf(av[i], bv[j], acc[i][j]);
    }
    __syncthreads();
  }

  #pragma unroll
  for (int i = 0; i < 8; i++) {
    int row = m0 + ty * 8 + i;
    #pragma unroll
    for (int jq = 0; jq < 2; jq++) {
      int col = n0 + tx * 8 + jq * 4;
      if (col < Nc) {
        float4 rv;
        rv.x = epi_apply<EPI>(acc[i][jq * 4 + 0], row, col + 0, Nc, e1, e2);
        rv.y = epi_apply<EPI>(acc[i][jq * 4 + 1], row, col + 1, Nc, e1, e2);
        rv.z = epi_apply<EPI>(acc[i][jq * 4 + 2], row, col + 2, Nc, e1, e2);
        rv.w = epi_apply<EPI>(acc[i][jq * 4 + 3], row, col + 3, Nc, e1, e2);
        *(float4*)(out + (size_t)row * Nc + col) = rv;
      }
    }
  }
}

// ---------------- WKV6 scan (per-chunk; b is chunk-local) ----------------
__global__ __launch_bounds__(256) void wkv_kernel(
    const float* __restrict__ r_g, const float* __restrict__ k_g,
    const float* __restrict__ v_g, const float* __restrict__ w_g,
    const float* __restrict__ u_g, float* __restrict__ o,
    float* __restrict__ Sf)
{
  const int blk = blockIdx.x;
  const int bh = blk >> 1, half = blk & 1;
  const int b = bh >> 4, h = bh & 15;
  const int tid = threadIdx.x, wid = tid >> 6, lane = tid & 63;
  const int sub = lane & 7, mloc = lane >> 3;
  const int m = half * 32 + wid * 8 + mloc;
  float s[8] = {0.f, 0.f, 0.f, 0.f, 0.f, 0.f, 0.f, 0.f};
  float ur[8];
  #pragma unroll
  for (int i = 0; i < 8; i++) ur[i] = u_g[h * Nn + sub * 8 + i];
  __shared__ float st[2][4][Nn];
  const float* tens = (wid == 0) ? r_g : (wid == 1) ? k_g : (wid == 2) ? v_g : w_g;
  const size_t base = (size_t)b * Tn * Cn + h * Nn;
  st[0][wid][lane] = tens[base + lane];
  __syncthreads();
  for (int t = 0; t < Tn; ++t) {
    const int cb = t & 1;
    float nxt = 0.f;
    if (t + 1 < Tn) nxt = tens[base + (size_t)(t + 1) * Cn + lane];
    const float vm = st[cb][2][m];
    const float4* r4 = (const float4*)&st[cb][0][sub * 8];
    const float4* k4 = (const float4*)&st[cb][1][sub * 8];
    const float4* w4 = (const float4*)&st[cb][3][sub * 8];
    float4 ra = r4[0], rb = r4[1], ka = k4[0], kb = k4[1], wa = w4[0], wb = w4[1];
    float rv[8] = {ra.x, ra.y, ra.z, ra.w, rb.x, rb.y, rb.z, rb.w};
    float kv[8] = {ka.x, ka.y, ka.z, ka.w, kb.x, kb.y, kb.z, kb.w};
    float wv[8] = {wa.x, wa.y, wa.z, wa.w, wb.x, wb.y, wb.z, wb.w};
    float oacc = 0.f;
    #pragma unroll
    for (int i = 0; i < 8; i++) {
      float kvp = kv[i] * vm;
      oacc += rv[i] * fmaf(ur[i], kvp, s[i]);
      s[i] = fmaf(wv[i], s[i], kvp);
    }
    oacc += __shfl_xor(oacc, 1);
    oacc += __shfl_xor(oacc, 2);
    oacc += __shfl_xor(oacc, 4);
    if (sub == 0) o[base + (size_t)t * Cn + m] = oacc;
    if (t + 1 < Tn) st[cb ^ 1][wid][lane] = nxt;
    __syncthreads();
  }
  #pragma unroll
  for (int i = 0; i < 8; i++)
    Sf[((size_t)(b * Hn + h) * Nn + (sub * 8 + i)) * Nn + m] = s[i];
}

// ---------------- launcher ----------------
static void launch_gemm(hipStream_t st, int epi, const float* A, int ldA,
                        const float* W, float* out, int M, int Nc, int K,
                        const float* e1 = nullptr, const float* e2 = nullptr)
{
  dim3 g((Nc + 127) / 128, M / 128), blk(256);
  switch (epi) {
    case EPI_NONE:    gemm_kernel<EPI_NONE><<<g, blk, 0, st>>>(A, ldA, W, out, Nc, K, e1, e2); break;
    case EPI_TANH:    gemm_kernel<EPI_TANH><<<g, blk, 0, st>>>(A, ldA, W, out, Nc, K, e1, e2); break;
    case EPI_SILU:    gemm_kernel<EPI_SILU><<<g, blk, 0, st>>>(A, ldA, W, out, Nc, K, e1, e2); break;
    case EPI_SIGMOID: gemm_kernel<EPI_SIGMOID><<<g, blk, 0, st>>>(A, ldA, W, out, Nc, K, e1, e2); break;
    case EPI_RELU2:   gemm_kernel<EPI_RELU2><<<g, blk, 0, st>>>(A, ldA, W, out, Nc, K, e1, e2); break;
    case EPI_DECAY:   gemm_kernel<EPI_DECAY><<<g, blk, 0, st>>>(A, ldA, W, out, Nc, K, e1, e2); break;
    case EPI_RESID:   gemm_kernel<EPI_RESID><<<g, blk, 0, st>>>(A, ldA, W, out, Nc, K, e1, e2); break;
    case EPI_MULADD:  gemm_kernel<EPI_MULADD><<<g, blk, 0, st>>>(A, ldA, W, out, Nc, K, e1, e2); break;
    default:          gemm_kernel<EPI_MIX><<<g, blk, 0, st>>>(A, ldA, W, out, Nc, K, e1, e2); break;
  }
}

extern "C" void kernel_launch(void* const* d_in, const int* in_sizes, int n_in,
                              void* d_out, int out_size, void* d_ws, size_t ws_size,
                              hipStream_t stream)
{
  const float* x        = (const float*)d_in[0];
  const float* ln0_g    = (const float*)d_in[1];
  const float* ln0_b    = (const float*)d_in[2];
  const float* ln1_g    = (const float*)d_in[3];
  const float* ln1_b    = (const float*)d_in[4];
  const float* ln2_g    = (const float*)d_in[5];
  const float* ln2_b    = (const float*)d_in[6];
  const float* lnx_g    = (const float*)d_in[7];
  const float* lnx_b    = (const float*)d_in[8];
  const float* maa_x    = (const float*)d_in[9];
  const float* maa[5]   = {(const float*)d_in[10], (const float*)d_in[11],
                           (const float*)d_in[12], (const float*)d_in[13],
                           (const float*)d_in[14]};            // w,k,v,r,g
  const float* tm_w1    = (const float*)d_in[15];
  const float* tm_w2    = (const float*)d_in[16];
  const float* tdecay   = (const float*)d_in[17];
  const float* td_w1    = (const float*)d_in[18];
  const float* td_w2    = (const float*)d_in[19];
  const float* faaaa    = (const float*)d_in[20];
  const float* Wr       = (const float*)d_in[21];
  const float* Wk       = (const float*)d_in[22];
  const float* Wv       = (const float*)d_in[23];
  const float* Wg       = (const float*)d_in[24];
  const float* Wo       = (const float*)d_in[25];
  const float* fmaa_k   = (const float*)d_in[26];
  const float* fmaa_r   = (const float*)d_in[27];
  const float* Wk_ffn   = (const float*)d_in[28];
  const float* Wv_ffn   = (const float*)d_in[29];
  const float* Wr_ffn   = (const float*)d_in[30];

  float* out = (float*)d_out;          // [BTC] x_final, then [B*H*N*N] Sf
  float* Sf  = out + BTC;

  // pick largest batch-chunk Bc that fits ws_size
  int Bc = 0;
  for (int c = 8; c >= 1; c >>= 1) {
    size_t need = (size_t)c * Tn * ((size_t)Cn * 6 + 224) * 4;
    if (need <= ws_size) { Bc = c; break; }
  }
  if (Bc == 0) {
    // diagnostic fallback: ws too small for even 1-sequence chunking.
    size_t tot = BTC + (size_t)Bn * Hn * Nn * Nn;
    zero_kernel<<<2048, 256, 0, stream>>>(out, tot);
    return;
  }

  const int    R  = Bc * Tn;           // rows per chunk
  const size_t RC = (size_t)R * Cn;    // elements per full-C chunk slot
  float* s0 = (float*)d_ws;            // xa -> gate -> xrf -> kk[0..]
  float* s1 = s0 + RC;                 // mix tmp -> o -> kk
  float* s2 = s1 + RC;                 // r -> kk
  float* s3 = s2 + RC;                 // k -> kk(3.5 ends mid-s3? no: kk = [s0, s0+3.5RC))
  float* s4 = s3 + RC;                 // v -> xf -> rf
  float* s5 = s4 + RC;                 // wdec -> xkf
  float* lora = s0 + 6 * RC;           // R*160
  float* tdh  = lora + (size_t)R * 160; // R*64

  for (int b0 = 0; b0 < Bn; b0 += Bc) {
    const size_t r0C = (size_t)b0 * Tn * Cn;
    const float* xc  = x + r0C;
    float*       x01 = out + r0C;      // x0 / x1 / final rows for this chunk
    float*       Sfc = Sf + (size_t)b0 * Hn * Nn * Nn;

    // ---- time-mix phase ----
    ln01_kernel<<<R, 256, 0, stream>>>(xc, ln0_g, ln0_b, ln1_g, ln1_b, x01, s0);
    mixshift_kernel<<<2048, 256, 0, stream>>>(s0, maa_x, s1, nullptr, nullptr, RC / 4);
    launch_gemm(stream, EPI_TANH, s1, Cn, tm_w1, lora, R, 160, Cn);
    // f=0 (w): mix -> s1, tanh-lora -> tdh, decay -> s5
    launch_gemm(stream, EPI_MIX, lora + 0 * 32, 160, tm_w2 + (size_t)0 * 32 * Cn, s1, R, Cn, 32, s0, maa[0]);
    launch_gemm(stream, EPI_TANH, s1, Cn, td_w1, tdh, R, 64, Cn);
    launch_gemm(stream, EPI_DECAY, tdh, 64, td_w2, s5, R, Cn, 64, tdecay);
    // f=1 (k): mix -> s1, k -> s3
    launch_gemm(stream, EPI_MIX, lora + 1 * 32, 160, tm_w2 + (size_t)1 * 32 * Cn, s1, R, Cn, 32, s0, maa[1]);
    launch_gemm(stream, EPI_NONE, s1, Cn, Wk, s3, R, Cn, Cn);
    // f=2 (v): mix -> s1, v -> s4
    launch_gemm(stream, EPI_MIX, lora + 2 * 32, 160, tm_w2 + (size_t)2 * 32 * Cn, s1, R, Cn, 32, s0, maa[2]);
    launch_gemm(stream, EPI_NONE, s1, Cn, Wv, s4, R, Cn, Cn);
    // f=3 (r): mix -> s1, r -> s2
    launch_gemm(stream, EPI_MIX, lora + 3 * 32, 160, tm_w2 + (size_t)3 * 32 * Cn, s1, R, Cn, 32, s0, maa[3]);
    launch_gemm(stream, EPI_NONE, s1, Cn, Wr, s2, R, Cn, Cn);
    // f=4 (g): mix -> s1 (xa dead after this), gate -> s0
    launch_gemm(stream, EPI_MIX, lora + 4 * 32, 160, tm_w2 + (size_t)4 * 32 * Cn, s1, R, Cn, 32, s0, maa[4]);
    launch_gemm(stream, EPI_SILU, s1, Cn, Wg, s0, R, Cn, Cn);
    // WKV scan: (r,k,v,w) -> o in s1, final state -> Sfc
    wkv_kernel<<<Bc * 32, 256, 0, stream>>>(s2, s3, s4, s5, faaaa, s1, Sfc);
    // groupnorm * gate, in place on s1
    gn_kernel<<<R * Hn / 4, 256, 0, stream>>>(s1, lnx_g, lnx_b, s0);
    // x1 = x0 + o@Wo (in place in d_out rows)
    launch_gemm(stream, EPI_RESID, s1, Cn, Wo, x01, R, Cn, Cn, x01);

    // ---- channel-mix phase ----
    ln_kernel<<<R, 256, 0, stream>>>(x01, ln2_g, ln2_b, s4);                 // xf -> s4
    mixshift_kernel<<<2048, 256, 0, stream>>>(s4, fmaa_k, s5, fmaa_r, s0, RC / 4); // xkf->s5, xrf->s0
    launch_gemm(stream, EPI_SIGMOID, s0, Cn, Wr_ffn, s4, R, Cn, Cn);         // rf -> s4 (xf dead)
    launch_gemm(stream, EPI_RELU2, s5, Cn, Wk_ffn, s0, R, 3584, Cn);         // kk -> [s0, s0+3.5RC)
    launch_gemm(stream, EPI_MULADD, s0, 3584, Wv_ffn, x01, R, Cn, 3584, s4, x01);
  }
}

// Round 4
// 4472.882 us; speedup vs baseline: 1.8951x; 1.8951x over previous
//
#include <hip/hip_runtime.h>
#include <math.h>

// RWKV6 block forward. Large GEMMs on bf16 MFMA with hi/lo split precision
// (fp32-quality: acc = Ah*Bh + Ah*Bl + Al*Bh in fp32). Small GEMMs + WKV fp32.
// B=8 T=2048 C=1024 H=16 N=64 F=3584.

#define DEVI static __device__ __forceinline__

constexpr int Tn = 2048, Cn = 1024, Hn = 16, Nn = 64;
constexpr int Bn = 8;
constexpr size_t BTC = (size_t)Bn * Tn * Cn;

enum { EPI_NONE = 0, EPI_TANH, EPI_SILU, EPI_SIGMOID, EPI_RELU2,
       EPI_DECAY, EPI_RESID, EPI_MULADD, EPI_MIX };

typedef short s16x8 __attribute__((ext_vector_type(8)));
typedef float f32x4 __attribute__((ext_vector_type(4)));

// ---------------- bf16 split helpers ----------------
DEVI unsigned short f2bf(float f) {
  unsigned u = __float_as_uint(f);
  unsigned r = (u + 0x7FFFu + ((u >> 16) & 1u)) >> 16;
  return (unsigned short)r;
}
DEVI float bf2f(unsigned short h) { return __uint_as_float((unsigned)h << 16); }

DEVI void split_f4(float4 v, unsigned& hiA, unsigned& hiB, unsigned& loA, unsigned& loB) {
  unsigned short h0 = f2bf(v.x), h1 = f2bf(v.y), h2 = f2bf(v.z), h3 = f2bf(v.w);
  unsigned short l0 = f2bf(v.x - bf2f(h0)), l1 = f2bf(v.y - bf2f(h1));
  unsigned short l2 = f2bf(v.z - bf2f(h2)), l3 = f2bf(v.w - bf2f(h3));
  hiA = (unsigned)h0 | ((unsigned)h1 << 16); hiB = (unsigned)h2 | ((unsigned)h3 << 16);
  loA = (unsigned)l0 | ((unsigned)l1 << 16); loB = (unsigned)l2 | ((unsigned)l3 << 16);
}

// ---------------- reductions ----------------
DEVI float wave_sum(float v) {
  v += __shfl_xor(v, 32); v += __shfl_xor(v, 16); v += __shfl_xor(v, 8);
  v += __shfl_xor(v, 4);  v += __shfl_xor(v, 2);  v += __shfl_xor(v, 1);
  return v;
}

DEVI float blk_sum(float v, float* sb) {
  v = wave_sum(v);
  int tid = threadIdx.x;
  if ((tid & 63) == 0) sb[tid >> 6] = v;
  __syncthreads();
  v = sb[0] + sb[1] + sb[2] + sb[3];
  __syncthreads();
  return v;
}

// ---------------- misc ----------------
__global__ __launch_bounds__(256) void zero_kernel(float* p, size_t n) {
  for (size_t i = (size_t)blockIdx.x * 256 + threadIdx.x; i < n;
       i += (size_t)gridDim.x * 256) p[i] = 0.f;
}

// ---------------- weight transpose + bf16 split: W[K][N] -> Th/Tl[N][K] ----------------
__global__ __launch_bounds__(256) void tsplit_kernel(
    const float* __restrict__ W, int K, int N,
    unsigned short* __restrict__ Th, unsigned short* __restrict__ Tl)
{
  __shared__ float tile[64][68];
  const int t = threadIdx.x;
  const int k0 = blockIdx.y * 64, n0 = blockIdx.x * 64;
  const int rr = t >> 4, cc = (t & 15) * 4;
  #pragma unroll
  for (int i = 0; i < 4; i++) {
    float4 v = *(const float4*)(W + (size_t)(k0 + rr + i * 16) * N + n0 + cc);
    tile[rr + i * 16][cc + 0] = v.x; tile[rr + i * 16][cc + 1] = v.y;
    tile[rr + i * 16][cc + 2] = v.z; tile[rr + i * 16][cc + 3] = v.w;
  }
  __syncthreads();
  #pragma unroll
  for (int i = 0; i < 4; i++) {
    int n = rr + i * 16;
    float4 f = make_float4(tile[cc + 0][n], tile[cc + 1][n],
                           tile[cc + 2][n], tile[cc + 3][n]);
    uint2 H, L;
    split_f4(f, H.x, H.y, L.x, L.y);
    size_t o = (size_t)(n0 + n) * K + k0 + cc;
    *(uint2*)(Th + o) = H;
    *(uint2*)(Tl + o) = L;
  }
}

// ---------------- LayerNorm kernels ----------------
__global__ __launch_bounds__(256) void ln01_kernel(
    const float* __restrict__ x,
    const float* __restrict__ g0, const float* __restrict__ b0,
    const float* __restrict__ g1, const float* __restrict__ b1,
    float* __restrict__ x0, float* __restrict__ xa)
{
  __shared__ float sb[4];
  const int tid = threadIdx.x;
  const size_t base = (size_t)blockIdx.x * Cn + tid * 4;
  float4 v = *(const float4*)(x + base);
  float mean = blk_sum(v.x + v.y + v.z + v.w, sb) * (1.f / Cn);
  float4 d = make_float4(v.x - mean, v.y - mean, v.z - mean, v.w - mean);
  float var = blk_sum(d.x*d.x + d.y*d.y + d.z*d.z + d.w*d.w, sb) * (1.f / Cn);
  float rs = rsqrtf(var + 1e-5f);
  float4 gg = *(const float4*)(g0 + tid * 4), bb = *(const float4*)(b0 + tid * 4);
  float4 y = make_float4(d.x*rs*gg.x + bb.x, d.y*rs*gg.y + bb.y,
                         d.z*rs*gg.z + bb.z, d.w*rs*gg.w + bb.w);
  *(float4*)(x0 + base) = y;
  float mean2 = blk_sum(y.x + y.y + y.z + y.w, sb) * (1.f / Cn);
  float4 d2 = make_float4(y.x - mean2, y.y - mean2, y.z - mean2, y.w - mean2);
  float var2 = blk_sum(d2.x*d2.x + d2.y*d2.y + d2.z*d2.z + d2.w*d2.w, sb) * (1.f / Cn);
  float rs2 = rsqrtf(var2 + 1e-5f);
  gg = *(const float4*)(g1 + tid * 4); bb = *(const float4*)(b1 + tid * 4);
  *(float4*)(xa + base) = make_float4(d2.x*rs2*gg.x + bb.x, d2.y*rs2*gg.y + bb.y,
                                      d2.z*rs2*gg.z + bb.z, d2.w*rs2*gg.w + bb.w);
}

__global__ __launch_bounds__(256) void ln_kernel(
    const float* __restrict__ in, const float* __restrict__ g,
    const float* __restrict__ b, float* __restrict__ out)
{
  __shared__ float sb[4];
  const int tid = threadIdx.x;
  const size_t base = (size_t)blockIdx.x * Cn + tid * 4;
  float4 v = *(const float4*)(in + base);
  float mean = blk_sum(v.x + v.y + v.z + v.w, sb) * (1.f / Cn);
  float4 d = make_float4(v.x - mean, v.y - mean, v.z - mean, v.w - mean);
  float var = blk_sum(d.x*d.x + d.y*d.y + d.z*d.z + d.w*d.w, sb) * (1.f / Cn);
  float rs = rsqrtf(var + 1e-5f);
  float4 gg = *(const float4*)(g + tid * 4), bb = *(const float4*)(b + tid * 4);
  *(float4*)(out + base) = make_float4(d.x*rs*gg.x + bb.x, d.y*rs*gg.y + bb.y,
                                       d.z*rs*gg.z + bb.z, d.w*rs*gg.w + bb.w);
}

// per-head groupnorm (over N=64) * lnx affine * gate, in-place on o.
__global__ __launch_bounds__(256) void gn_kernel(
    float* o, const float* __restrict__ g, const float* __restrict__ b,
    const float* __restrict__ gate)
{
  const int tid = threadIdx.x;
  const int row = blockIdx.x * 4 + (tid >> 6);
  const int lane = tid & 63;
  const size_t idx = (size_t)row * Nn + lane;
  float val = o[idx];
  float mean = wave_sum(val) * (1.f / Nn);
  float d = val - mean;
  float var = wave_sum(d * d) * (1.f / Nn);
  float rs = rsqrtf(var + 1e-5f);
  int c = (row & (Hn - 1)) * Nn + lane;
  o[idx] = (d * rs * g[c] + b[c]) * gate[idx];
}

// token-shift mix: out = x + (shift(x)-x)*maa  (one or two outputs)
__global__ __launch_bounds__(256) void mixshift_kernel(
    const float* __restrict__ xin,
    const float* __restrict__ maaA, float* __restrict__ outA,
    const float* __restrict__ maaB, float* __restrict__ outB, size_t n4)
{
  const int C4 = Cn / 4;
  for (size_t i = (size_t)blockIdx.x * 256 + threadIdx.x; i < n4;
       i += (size_t)gridDim.x * 256) {
    int c4 = (int)(i & (C4 - 1));
    size_t bt = i >> 8;
    float4 cur = ((const float4*)xin)[i];
    float4 prev = make_float4(0.f, 0.f, 0.f, 0.f);
    if (bt % Tn) prev = ((const float4*)xin)[i - C4];
    float4 ma = ((const float4*)maaA)[c4];
    ((float4*)outA)[i] = make_float4(
        cur.x + (prev.x - cur.x) * ma.x, cur.y + (prev.y - cur.y) * ma.y,
        cur.z + (prev.z - cur.z) * ma.z, cur.w + (prev.w - cur.w) * ma.w);
    if (maaB) {
      float4 mb = ((const float4*)maaB)[c4];
      ((float4*)outB)[i] = make_float4(
          cur.x + (prev.x - cur.x) * mb.x, cur.y + (prev.y - cur.y) * mb.y,
          cur.z + (prev.z - cur.z) * mb.z, cur.w + (prev.w - cur.w) * mb.w);
    }
  }
}

// ---------------- shared epilogue ----------------
template<int EPI>
DEVI float epi_apply(float v, int row, int col, int Nc,
                     const float* e1, const float* e2)
{
  if constexpr (EPI == EPI_NONE) { return v; }
  else if constexpr (EPI == EPI_TANH) { return tanhf(v); }
  else if constexpr (EPI == EPI_SILU) { return v / (1.f + expf(-v)); }
  else if constexpr (EPI == EPI_SIGMOID) { return 1.f / (1.f + expf(-v)); }
  else if constexpr (EPI == EPI_RELU2) { float r = fmaxf(v, 0.f); return r * r; }
  else if constexpr (EPI == EPI_DECAY) { return expf(-expf(v + e1[col])); }
  else if constexpr (EPI == EPI_RESID) { return v + e1[(size_t)row * Nc + col]; }
  else if constexpr (EPI == EPI_MULADD) {
    size_t i = (size_t)row * Nc + col; return v * e1[i] + e2[i];
  } else { // EPI_MIX
    size_t i = (size_t)row * Nc + col;
    float cur = e1[i];
    float prev = (row % Tn) ? e1[i - Cn] : 0.f;
    return cur + (prev - cur) * (e2[col] + v);
  }
}

// ---------------- fp32 vector GEMM (small K / small N only) ----------------
template<int EPI>
__global__ __launch_bounds__(256) void gemm_kernel(
    const float* __restrict__ A, int ldA,
    const float* __restrict__ W, float* out, int Nc, int K,
    const float* e1, const float* e2)
{
  constexpr int BK = 16;
  __shared__ float As[BK][132];
  __shared__ float Bs[BK][128];
  const int tid = threadIdx.x;
  const int m0 = blockIdx.y * 128, n0 = blockIdx.x * 128;
  const int tx = tid & 15, ty = tid >> 4;
  const int am = tid >> 2, ak = (tid & 3) << 2;
  const int bn = (tid & 31) << 2, bk = tid >> 5;

  float acc[8][8];
  #pragma unroll
  for (int i = 0; i < 8; i++)
    #pragma unroll
    for (int j = 0; j < 8; j++) acc[i][j] = 0.f;

  for (int k0 = 0; k0 < K; k0 += BK) {
    float4 va = *(const float4*)(A + (size_t)(m0 + am) * ldA + k0 + ak);
    float4 vb = *(const float4*)(A + (size_t)(m0 + 64 + am) * ldA + k0 + ak);
    float4 w1 = make_float4(0.f, 0.f, 0.f, 0.f);
    float4 w2 = make_float4(0.f, 0.f, 0.f, 0.f);
    if (n0 + bn < Nc) {
      w1 = *(const float4*)(W + (size_t)(k0 + bk) * Nc + n0 + bn);
      w2 = *(const float4*)(W + (size_t)(k0 + bk + 8) * Nc + n0 + bn);
    }
    As[ak + 0][am] = va.x; As[ak + 1][am] = va.y;
    As[ak + 2][am] = va.z; As[ak + 3][am] = va.w;
    As[ak + 0][64 + am] = vb.x; As[ak + 1][64 + am] = vb.y;
    As[ak + 2][64 + am] = vb.z; As[ak + 3][64 + am] = vb.w;
    *(float4*)&Bs[bk][bn] = w1;
    *(float4*)&Bs[bk + 8][bn] = w2;
    __syncthreads();
    #pragma unroll
    for (int kk = 0; kk < BK; kk++) {
      float4 a0 = *(const float4*)&As[kk][ty * 8];
      float4 a1 = *(const float4*)&As[kk][ty * 8 + 4];
      float4 b0 = *(const float4*)&Bs[kk][tx * 8];
      float4 b1 = *(const float4*)&Bs[kk][tx * 8 + 4];
      float av[8] = {a0.x, a0.y, a0.z, a0.w, a1.x, a1.y, a1.z, a1.w};
      float bv[8] = {b0.x, b0.y, b0.z, b0.w, b1.x, b1.y, b1.z, b1.w};
      #pragma unroll
      for (int i = 0; i < 8; i++)
        #pragma unroll
        for (int j = 0; j < 8; j++)
          acc[i][j] = fmaf(av[i], bv[j], acc[i][j]);
    }
    __syncthreads();
  }

  #pragma unroll
  for (int i = 0; i < 8; i++) {
    int row = m0 + ty * 8 + i;
    #pragma unroll
    for (int jq = 0; jq < 2; jq++) {
      int col = n0 + tx * 8 + jq * 4;
      if (col < Nc) {
        float4 rv;
        rv.x = epi_apply<EPI>(acc[i][jq * 4 + 0], row, col + 0, Nc, e1, e2);
        rv.y = epi_apply<EPI>(acc[i][jq * 4 + 1], row, col + 1, Nc, e1, e2);
        rv.z = epi_apply<EPI>(acc[i][jq * 4 + 2], row, col + 2, Nc, e1, e2);
        rv.w = epi_apply<EPI>(acc[i][jq * 4 + 3], row, col + 3, Nc, e1, e2);
        *(float4*)(out + (size_t)row * Nc + col) = rv;
      }
    }
  }
}

// ---------------- MFMA split-bf16 GEMM: out = A[M,K](f32) @ WT[N,K](bf16 hi/lo) ----------------
// 128x128 tile, BK=32, 4 waves in 2x2; per wave 4x4 frags of 16x16x32.
// acc = Ah*Bh + Ah*Bl + Al*Bh  (fp32-quality).
template<int EPI>
__global__ __launch_bounds__(256) void gemm_mfma(
    const float* __restrict__ A, int ldA,
    const unsigned short* __restrict__ BTh, const unsigned short* __restrict__ BTl,
    float* __restrict__ out, int Nc, int K,
    const float* __restrict__ e1, const float* __restrict__ e2)
{
  __shared__ unsigned short Ah[128][40], Al[128][40], Bh[128][40], Bl[128][40];
  const int tid = threadIdx.x;
  const int m0 = blockIdx.y * 128, n0 = blockIdx.x * 128;
  const int wid = tid >> 6, lane = tid & 63;
  const int wm = (wid >> 1) * 64, wn = (wid & 1) * 64;
  const int fr = lane & 15, fq = lane >> 4;    // frag row/col, k-group
  const int sr = tid >> 1, sc = (tid & 1) * 16; // staging row, col (halves)

  f32x4 acc[4][4] = {};

  for (int k0 = 0; k0 < K; k0 += 32) {
    // stage A: 128x32 fp32 -> split bf16 hi/lo
    const float* Ap = A + (size_t)(m0 + sr) * ldA + k0 + sc;
    float4 a0 = *(const float4*)(Ap + 0);
    float4 a1 = *(const float4*)(Ap + 4);
    float4 a2 = *(const float4*)(Ap + 8);
    float4 a3 = *(const float4*)(Ap + 12);
    uint4 H, L;
    split_f4(a0, H.x, H.y, L.x, L.y);
    split_f4(a1, H.z, H.w, L.z, L.w);
    *(uint4*)&Ah[sr][sc] = H; *(uint4*)&Al[sr][sc] = L;
    split_f4(a2, H.x, H.y, L.x, L.y);
    split_f4(a3, H.z, H.w, L.z, L.w);
    *(uint4*)&Ah[sr][sc + 8] = H; *(uint4*)&Al[sr][sc + 8] = L;
    // stage B: rows n0..n0+127 of WT[N][K], cols k0..k0+31 (already bf16)
    const unsigned short* Bp = BTh + (size_t)(n0 + sr) * K + k0 + sc;
    const unsigned short* Bq = BTl + (size_t)(n0 + sr) * K + k0 + sc;
    *(uint4*)&Bh[sr][sc] = *(const uint4*)Bp;
    *(uint4*)&Bh[sr][sc + 8] = *(const uint4*)(Bp + 8);
    *(uint4*)&Bl[sr][sc] = *(const uint4*)Bq;
    *(uint4*)&Bl[sr][sc + 8] = *(const uint4*)(Bq + 8);
    __syncthreads();

    s16x8 fah[4], fal[4], fbh[4], fbl[4];
    #pragma unroll
    for (int i = 0; i < 4; i++) {
      fah[i] = *(const s16x8*)&Ah[wm + i * 16 + fr][fq * 8];
      fal[i] = *(const s16x8*)&Al[wm + i * 16 + fr][fq * 8];
      fbh[i] = *(const s16x8*)&Bh[wn + i * 16 + fr][fq * 8];
      fbl[i] = *(const s16x8*)&Bl[wn + i * 16 + fr][fq * 8];
    }
    #pragma unroll
    for (int i = 0; i < 4; i++)
      #pragma unroll
      for (int j = 0; j < 4; j++) {
        acc[i][j] = __builtin_amdgcn_mfma_f32_16x16x32_bf16(fah[i], fbh[j], acc[i][j], 0, 0, 0);
        acc[i][j] = __builtin_amdgcn_mfma_f32_16x16x32_bf16(fah[i], fbl[j], acc[i][j], 0, 0, 0);
        acc[i][j] = __builtin_amdgcn_mfma_f32_16x16x32_bf16(fal[i], fbh[j], acc[i][j], 0, 0, 0);
      }
    __syncthreads();
  }

  // epilogue: C/D layout col=lane&15, row=(lane>>4)*4+q  [guide §3, m89]
  #pragma unroll
  for (int i = 0; i < 4; i++)
    #pragma unroll
    for (int j = 0; j < 4; j++)
      #pragma unroll
      for (int q = 0; q < 4; q++) {
        int row = m0 + wm + i * 16 + fq * 4 + q;
        int col = n0 + wn + j * 16 + fr;
        out[(size_t)row * Nc + col] =
            epi_apply<EPI>(acc[i][j][q], row, col, Nc, e1, e2);
      }
}

// ---------------- WKV6 scan (per-chunk; b is chunk-local) ----------------
__global__ __launch_bounds__(256) void wkv_kernel(
    const float* __restrict__ r_g, const float* __restrict__ k_g,
    const float* __restrict__ v_g, const float* __restrict__ w_g,
    const float* __restrict__ u_g, float* __restrict__ o,
    float* __restrict__ Sf)
{
  const int blk = blockIdx.x;
  const int bh = blk >> 1, half = blk & 1;
  const int b = bh >> 4, h = bh & 15;
  const int tid = threadIdx.x, wid = tid >> 6, lane = tid & 63;
  const int sub = lane & 7, mloc = lane >> 3;
  const int m = half * 32 + wid * 8 + mloc;
  float s[8] = {0.f, 0.f, 0.f, 0.f, 0.f, 0.f, 0.f, 0.f};
  float ur[8];
  #pragma unroll
  for (int i = 0; i < 8; i++) ur[i] = u_g[h * Nn + sub * 8 + i];
  __shared__ float st[2][4][Nn];
  const float* tens = (wid == 0) ? r_g : (wid == 1) ? k_g : (wid == 2) ? v_g : w_g;
  const size_t base = (size_t)b * Tn * Cn + h * Nn;
  st[0][wid][lane] = tens[base + lane];
  __syncthreads();
  for (int t = 0; t < Tn; ++t) {
    const int cb = t & 1;
    float nxt = 0.f;
    if (t + 1 < Tn) nxt = tens[base + (size_t)(t + 1) * Cn + lane];
    const float vm = st[cb][2][m];
    const float4* r4 = (const float4*)&st[cb][0][sub * 8];
    const float4* k4 = (const float4*)&st[cb][1][sub * 8];
    const float4* w4 = (const float4*)&st[cb][3][sub * 8];
    float4 ra = r4[0], rb = r4[1], ka = k4[0], kb = k4[1], wa = w4[0], wb = w4[1];
    float rv[8] = {ra.x, ra.y, ra.z, ra.w, rb.x, rb.y, rb.z, rb.w};
    float kv[8] = {ka.x, ka.y, ka.z, ka.w, kb.x, kb.y, kb.z, kb.w};
    float wv[8] = {wa.x, wa.y, wa.z, wa.w, wb.x, wb.y, wb.z, wb.w};
    float oacc = 0.f;
    #pragma unroll
    for (int i = 0; i < 8; i++) {
      float kvp = kv[i] * vm;
      oacc += rv[i] * fmaf(ur[i], kvp, s[i]);
      s[i] = fmaf(wv[i], s[i], kvp);
    }
    oacc += __shfl_xor(oacc, 1);
    oacc += __shfl_xor(oacc, 2);
    oacc += __shfl_xor(oacc, 4);
    if (sub == 0) o[base + (size_t)t * Cn + m] = oacc;
    if (t + 1 < Tn) st[cb ^ 1][wid][lane] = nxt;
    __syncthreads();
  }
  #pragma unroll
  for (int i = 0; i < 8; i++)
    Sf[((size_t)(b * Hn + h) * Nn + (sub * 8 + i)) * Nn + m] = s[i];
}

// ---------------- launchers ----------------
static void launch_gemm(hipStream_t st, int epi, const float* A, int ldA,
                        const float* W, float* out, int M, int Nc, int K,
                        const float* e1 = nullptr, const float* e2 = nullptr)
{
  dim3 g((Nc + 127) / 128, M / 128), blk(256);
  switch (epi) {
    case EPI_TANH:    gemm_kernel<EPI_TANH><<<g, blk, 0, st>>>(A, ldA, W, out, Nc, K, e1, e2); break;
    case EPI_DECAY:   gemm_kernel<EPI_DECAY><<<g, blk, 0, st>>>(A, ldA, W, out, Nc, K, e1, e2); break;
    default:          gemm_kernel<EPI_MIX><<<g, blk, 0, st>>>(A, ldA, W, out, Nc, K, e1, e2); break;
  }
}

static void launch_mfma(hipStream_t st, int epi, const float* A, int ldA,
                        const unsigned short* Bh, const unsigned short* Bl,
                        float* out, int M, int Nc, int K,
                        const float* e1 = nullptr, const float* e2 = nullptr)
{
  dim3 g(Nc / 128, M / 128), blk(256);
  switch (epi) {
    case EPI_NONE:    gemm_mfma<EPI_NONE><<<g, blk, 0, st>>>(A, ldA, Bh, Bl, out, Nc, K, e1, e2); break;
    case EPI_SILU:    gemm_mfma<EPI_SILU><<<g, blk, 0, st>>>(A, ldA, Bh, Bl, out, Nc, K, e1, e2); break;
    case EPI_SIGMOID: gemm_mfma<EPI_SIGMOID><<<g, blk, 0, st>>>(A, ldA, Bh, Bl, out, Nc, K, e1, e2); break;
    case EPI_RELU2:   gemm_mfma<EPI_RELU2><<<g, blk, 0, st>>>(A, ldA, Bh, Bl, out, Nc, K, e1, e2); break;
    case EPI_RESID:   gemm_mfma<EPI_RESID><<<g, blk, 0, st>>>(A, ldA, Bh, Bl, out, Nc, K, e1, e2); break;
    default:          gemm_mfma<EPI_MULADD><<<g, blk, 0, st>>>(A, ldA, Bh, Bl, out, Nc, K, e1, e2); break;
  }
}

extern "C" void kernel_launch(void* const* d_in, const int* in_sizes, int n_in,
                              void* d_out, int out_size, void* d_ws, size_t ws_size,
                              hipStream_t stream)
{
  const float* x        = (const float*)d_in[0];
  const float* ln0_g    = (const float*)d_in[1];
  const float* ln0_b    = (const float*)d_in[2];
  const float* ln1_g    = (const float*)d_in[3];
  const float* ln1_b    = (const float*)d_in[4];
  const float* ln2_g    = (const float*)d_in[5];
  const float* ln2_b    = (const float*)d_in[6];
  const float* lnx_g    = (const float*)d_in[7];
  const float* lnx_b    = (const float*)d_in[8];
  const float* maa_x    = (const float*)d_in[9];
  const float* maa[5]   = {(const float*)d_in[10], (const float*)d_in[11],
                           (const float*)d_in[12], (const float*)d_in[13],
                           (const float*)d_in[14]};            // w,k,v,r,g
  const float* tm_w1    = (const float*)d_in[15];
  const float* tm_w2    = (const float*)d_in[16];
  const float* tdecay   = (const float*)d_in[17];
  const float* td_w1    = (const float*)d_in[18];
  const float* td_w2    = (const float*)d_in[19];
  const float* faaaa    = (const float*)d_in[20];
  const float* Wr       = (const float*)d_in[21];
  const float* Wk       = (const float*)d_in[22];
  const float* Wv       = (const float*)d_in[23];
  const float* Wg       = (const float*)d_in[24];
  const float* Wo       = (const float*)d_in[25];
  const float* fmaa_k   = (const float*)d_in[26];
  const float* fmaa_r   = (const float*)d_in[27];
  const float* Wk_ffn   = (const float*)d_in[28];
  const float* Wv_ffn   = (const float*)d_in[29];
  const float* Wr_ffn   = (const float*)d_in[30];

  float* out = (float*)d_out;          // [BTC] x_final, then [B*H*N*N] Sf
  float* Sf  = out + BTC;

  // ---- ws layout: [WT bf16 hi/lo area][chunk slots] ----
  const size_t M1 = 1024 * 1024, M35 = (size_t)1024 * 3584;
  unsigned short* wt = (unsigned short*)d_ws;
  size_t off = 0;
  auto ualloc = [&](size_t n) { unsigned short* p = wt + off; off += n; return p; };
  unsigned short *Tr_h = ualloc(M1),  *Tr_l = ualloc(M1);
  unsigned short *Tk_h = ualloc(M1),  *Tk_l = ualloc(M1);
  unsigned short *Tv_h = ualloc(M1),  *Tv_l = ualloc(M1);
  unsigned short *Tg_h = ualloc(M1),  *Tg_l = ualloc(M1);
  unsigned short *To_h = ualloc(M1),  *To_l = ualloc(M1);
  unsigned short *Trf_h = ualloc(M1), *Trf_l = ualloc(M1);
  unsigned short *Tkf_h = ualloc(M35), *Tkf_l = ualloc(M35);   // [3584][1024]
  unsigned short *Tvf_h = ualloc(M35), *Tvf_l = ualloc(M35);   // [1024][3584]
  const size_t wt_bytes = off * 2;

  // pick largest batch-chunk Bc whose slots fit after the WT area
  int Bc = 0;
  for (int c = 8; c >= 1; c >>= 1) {
    size_t need = wt_bytes + (size_t)c * Tn * ((size_t)Cn * 6 + 224) * 4;
    if (need <= ws_size) { Bc = c; break; }
  }
  if (Bc == 0) {
    size_t tot = BTC + (size_t)Bn * Hn * Nn * Nn;
    zero_kernel<<<2048, 256, 0, stream>>>(out, tot);
    return;
  }

  // ---- weight transpose+split (once per call) ----
  tsplit_kernel<<<dim3(16, 16), 256, 0, stream>>>(Wr, 1024, 1024, Tr_h, Tr_l);
  tsplit_kernel<<<dim3(16, 16), 256, 0, stream>>>(Wk, 1024, 1024, Tk_h, Tk_l);
  tsplit_kernel<<<dim3(16, 16), 256, 0, stream>>>(Wv, 1024, 1024, Tv_h, Tv_l);
  tsplit_kernel<<<dim3(16, 16), 256, 0, stream>>>(Wg, 1024, 1024, Tg_h, Tg_l);
  tsplit_kernel<<<dim3(16, 16), 256, 0, stream>>>(Wo, 1024, 1024, To_h, To_l);
  tsplit_kernel<<<dim3(16, 16), 256, 0, stream>>>(Wr_ffn, 1024, 1024, Trf_h, Trf_l);
  tsplit_kernel<<<dim3(56, 16), 256, 0, stream>>>(Wk_ffn, 1024, 3584, Tkf_h, Tkf_l);
  tsplit_kernel<<<dim3(16, 56), 256, 0, stream>>>(Wv_ffn, 3584, 1024, Tvf_h, Tvf_l);

  const int    R  = Bc * Tn;
  const size_t RC = (size_t)R * Cn;
  float* s0 = (float*)(wt + off);
  float* s1 = s0 + RC;
  float* s2 = s1 + RC;
  float* s3 = s2 + RC;
  float* s4 = s3 + RC;
  float* s5 = s4 + RC;
  float* lora = s0 + 6 * RC;             // R*160
  float* tdh  = lora + (size_t)R * 160;  // R*64

  for (int b0 = 0; b0 < Bn; b0 += Bc) {
    const size_t r0C = (size_t)b0 * Tn * Cn;
    const float* xc  = x + r0C;
    float*       x01 = out + r0C;
    float*       Sfc = Sf + (size_t)b0 * Hn * Nn * Nn;

    // ---- time-mix phase ----
    ln01_kernel<<<R, 256, 0, stream>>>(xc, ln0_g, ln0_b, ln1_g, ln1_b, x01, s0);
    mixshift_kernel<<<2048, 256, 0, stream>>>(s0, maa_x, s1, nullptr, nullptr, RC / 4);
    launch_gemm(stream, EPI_TANH, s1, Cn, tm_w1, lora, R, 160, Cn);
    // f=0 (w): mix -> s1, tanh-lora -> tdh, decay -> s5
    launch_gemm(stream, EPI_MIX, lora + 0 * 32, 160, tm_w2 + (size_t)0 * 32 * Cn, s1, R, Cn, 32, s0, maa[0]);
    launch_gemm(stream, EPI_TANH, s1, Cn, td_w1, tdh, R, 64, Cn);
    launch_gemm(stream, EPI_DECAY, tdh, 64, td_w2, s5, R, Cn, 64, tdecay);
    // f=1 (k): mix -> s1, k -> s3
    launch_gemm(stream, EPI_MIX, lora + 1 * 32, 160, tm_w2 + (size_t)1 * 32 * Cn, s1, R, Cn, 32, s0, maa[1]);
    launch_mfma(stream, EPI_NONE, s1, Cn, Tk_h, Tk_l, s3, R, Cn, Cn);
    // f=2 (v): mix -> s1, v -> s4
    launch_gemm(stream, EPI_MIX, lora + 2 * 32, 160, tm_w2 + (size_t)2 * 32 * Cn, s1, R, Cn, 32, s0, maa[2]);
    launch_mfma(stream, EPI_NONE, s1, Cn, Tv_h, Tv_l, s4, R, Cn, Cn);
    // f=3 (r): mix -> s1, r -> s2
    launch_gemm(stream, EPI_MIX, lora + 3 * 32, 160, tm_w2 + (size_t)3 * 32 * Cn, s1, R, Cn, 32, s0, maa[3]);
    launch_mfma(stream, EPI_NONE, s1, Cn, Tr_h, Tr_l, s2, R, Cn, Cn);
    // f=4 (g): mix -> s1 (xa dead after), gate -> s0
    launch_gemm(stream, EPI_MIX, lora + 4 * 32, 160, tm_w2 + (size_t)4 * 32 * Cn, s1, R, Cn, 32, s0, maa[4]);
    launch_mfma(stream, EPI_SILU, s1, Cn, Tg_h, Tg_l, s0, R, Cn, Cn);
    // WKV scan: (r,k,v,w) -> o in s1, final state -> Sfc
    wkv_kernel<<<Bc * 32, 256, 0, stream>>>(s2, s3, s4, s5, faaaa, s1, Sfc);
    // groupnorm * gate, in place on s1
    gn_kernel<<<R * Hn / 4, 256, 0, stream>>>(s1, lnx_g, lnx_b, s0);
    // x1 = x0 + o@Wo
    launch_mfma(stream, EPI_RESID, s1, Cn, To_h, To_l, x01, R, Cn, Cn, x01);

    // ---- channel-mix phase ----
    ln_kernel<<<R, 256, 0, stream>>>(x01, ln2_g, ln2_b, s4);                    // xf -> s4
    mixshift_kernel<<<2048, 256, 0, stream>>>(s4, fmaa_k, s5, fmaa_r, s0, RC / 4); // xkf->s5, xrf->s0
    launch_mfma(stream, EPI_SIGMOID, s0, Cn, Trf_h, Trf_l, s4, R, Cn, Cn);      // rf -> s4
    launch_mfma(stream, EPI_RELU2, s5, Cn, Tkf_h, Tkf_l, s0, R, 3584, Cn);      // kk -> s0..s0+3.5RC
    launch_mfma(stream, EPI_MULADD, s0, 3584, Tvf_h, Tvf_l, x01, R, Cn, 3584, s4, x01);
  }
}

// Round 6
// 3569.617 us; speedup vs baseline: 2.3747x; 1.2530x over previous
//
#include <hip/hip_runtime.h>
#include <math.h>

// RWKV6 block forward. All large GEMMs: bf16 MFMA, hi/lo split operands
// (fp32 quality). WKV: chunked linear-attention scan (L=64) in fp32.
// B=8 T=2048 C=1024 H=16 N=64 F=3584.

#define DEVI static __device__ __forceinline__

constexpr int Tn = 2048, Cn = 1024, Hn = 16, Nn = 64;
constexpr int Bn = 8;
constexpr size_t BTC = (size_t)Bn * Tn * Cn;

enum { EPI_NONE = 0, EPI_TANH, EPI_SILU, EPI_SIGMOID, EPI_RELU2,
       EPI_EW, EPI_RESID, EPI_MA3, EPI_MIX };
enum { OM_F32 = 0, OM_SPLIT = 1 };

typedef short s16x8 __attribute__((ext_vector_type(8)));
typedef float f32x4 __attribute__((ext_vector_type(4)));
typedef unsigned short ushort_t;

// ---------------- bf16 split helpers ----------------
DEVI unsigned short f2bf(float f) {
  unsigned u = __float_as_uint(f);
  unsigned r = (u + 0x7FFFu + ((u >> 16) & 1u)) >> 16;
  return (unsigned short)r;
}
DEVI float bf2f(unsigned short h) { return __uint_as_float((unsigned)h << 16); }

DEVI void split_f4(float4 v, unsigned& hiA, unsigned& hiB, unsigned& loA, unsigned& loB) {
  unsigned short h0 = f2bf(v.x), h1 = f2bf(v.y), h2 = f2bf(v.z), h3 = f2bf(v.w);
  unsigned short l0 = f2bf(v.x - bf2f(h0)), l1 = f2bf(v.y - bf2f(h1));
  unsigned short l2 = f2bf(v.z - bf2f(h2)), l3 = f2bf(v.w - bf2f(h3));
  hiA = (unsigned)h0 | ((unsigned)h1 << 16); hiB = (unsigned)h2 | ((unsigned)h3 << 16);
  loA = (unsigned)l0 | ((unsigned)l1 << 16); loB = (unsigned)l2 | ((unsigned)l3 << 16);
}

// ---------------- reductions ----------------
DEVI float wave_sum(float v) {
  v += __shfl_xor(v, 32); v += __shfl_xor(v, 16); v += __shfl_xor(v, 8);
  v += __shfl_xor(v, 4);  v += __shfl_xor(v, 2);  v += __shfl_xor(v, 1);
  return v;
}
DEVI float blk_sum(float v, float* sb) {
  v = wave_sum(v);
  int tid = threadIdx.x;
  if ((tid & 63) == 0) sb[tid >> 6] = v;
  __syncthreads();
  v = sb[0] + sb[1] + sb[2] + sb[3];
  __syncthreads();
  return v;
}

// ---------------- misc ----------------
__global__ __launch_bounds__(256) void zero_kernel(float* p, size_t n) {
  for (size_t i = (size_t)blockIdx.x * 256 + threadIdx.x; i < n;
       i += (size_t)gridDim.x * 256) p[i] = 0.f;
}

// ---------------- weight transpose + split: W[K][N] -> Th/Tl[N][K], guarded ----------------
__global__ __launch_bounds__(256) void tsplit_kernel(
    const float* __restrict__ W, int K, int N,
    unsigned short* __restrict__ Th, unsigned short* __restrict__ Tl)
{
  __shared__ float tile[64][68];
  const int t = threadIdx.x;
  const int k0 = blockIdx.y * 64, n0 = blockIdx.x * 64;
  const int rr = t >> 4, cc = (t & 15) * 4;
  #pragma unroll
  for (int i = 0; i < 4; i++) {
    float4 v = make_float4(0.f, 0.f, 0.f, 0.f);
    if (n0 + cc + 3 < N)
      v = *(const float4*)(W + (size_t)(k0 + rr + i * 16) * N + n0 + cc);
    tile[rr + i * 16][cc + 0] = v.x; tile[rr + i * 16][cc + 1] = v.y;
    tile[rr + i * 16][cc + 2] = v.z; tile[rr + i * 16][cc + 3] = v.w;
  }
  __syncthreads();
  #pragma unroll
  for (int i = 0; i < 4; i++) {
    int n = rr + i * 16;
    if (n0 + n < N) {
      float4 f = make_float4(tile[cc + 0][n], tile[cc + 1][n],
                             tile[cc + 2][n], tile[cc + 3][n]);
      uint2 H, L;
      split_f4(f, H.x, H.y, L.x, L.y);
      size_t o = (size_t)(n0 + n) * K + k0 + cc;
      *(uint2*)(Th + o) = H;
      *(uint2*)(Tl + o) = L;
    }
  }
}

// ---------------- LayerNorm kernels ----------------
__global__ __launch_bounds__(256) void ln01_kernel(
    const float* __restrict__ x,
    const float* __restrict__ g0, const float* __restrict__ b0,
    const float* __restrict__ g1, const float* __restrict__ b1,
    float* __restrict__ x0, float* __restrict__ xa)
{
  __shared__ float sb[4];
  const int tid = threadIdx.x;
  const size_t base = (size_t)blockIdx.x * Cn + tid * 4;
  float4 v = *(const float4*)(x + base);
  float mean = blk_sum(v.x + v.y + v.z + v.w, sb) * (1.f / Cn);
  float4 d = make_float4(v.x - mean, v.y - mean, v.z - mean, v.w - mean);
  float var = blk_sum(d.x*d.x + d.y*d.y + d.z*d.z + d.w*d.w, sb) * (1.f / Cn);
  float rs = rsqrtf(var + 1e-5f);
  float4 gg = *(const float4*)(g0 + tid * 4), bb = *(const float4*)(b0 + tid * 4);
  float4 y = make_float4(d.x*rs*gg.x + bb.x, d.y*rs*gg.y + bb.y,
                         d.z*rs*gg.z + bb.z, d.w*rs*gg.w + bb.w);
  *(float4*)(x0 + base) = y;
  float mean2 = blk_sum(y.x + y.y + y.z + y.w, sb) * (1.f / Cn);
  float4 d2 = make_float4(y.x - mean2, y.y - mean2, y.z - mean2, y.w - mean2);
  float var2 = blk_sum(d2.x*d2.x + d2.y*d2.y + d2.z*d2.z + d2.w*d2.w, sb) * (1.f / Cn);
  float rs2 = rsqrtf(var2 + 1e-5f);
  gg = *(const float4*)(g1 + tid * 4); bb = *(const float4*)(b1 + tid * 4);
  *(float4*)(xa + base) = make_float4(d2.x*rs2*gg.x + bb.x, d2.y*rs2*gg.y + bb.y,
                                      d2.z*rs2*gg.z + bb.z, d2.w*rs2*gg.w + bb.w);
}

__global__ __launch_bounds__(256) void ln_kernel(
    const float* __restrict__ in, const float* __restrict__ g,
    const float* __restrict__ b, float* __restrict__ out)
{
  __shared__ float sb[4];
  const int tid = threadIdx.x;
  const size_t base = (size_t)blockIdx.x * Cn + tid * 4;
  float4 v = *(const float4*)(in + base);
  float mean = blk_sum(v.x + v.y + v.z + v.w, sb) * (1.f / Cn);
  float4 d = make_float4(v.x - mean, v.y - mean, v.z - mean, v.w - mean);
  float var = blk_sum(d.x*d.x + d.y*d.y + d.z*d.z + d.w*d.w, sb) * (1.f / Cn);
  float rs = rsqrtf(var + 1e-5f);
  float4 gg = *(const float4*)(g + tid * 4), bb = *(const float4*)(b + tid * 4);
  *(float4*)(out + base) = make_float4(d.x*rs*gg.x + bb.x, d.y*rs*gg.y + bb.y,
                                       d.z*rs*gg.z + bb.z, d.w*rs*gg.w + bb.w);
}

// groupnorm*gate -> bf16 split pair
__global__ __launch_bounds__(256) void gn_kernel(
    const float* __restrict__ o, const float* __restrict__ g,
    const float* __restrict__ b, const float* __restrict__ gate,
    unsigned short* __restrict__ oh, unsigned short* __restrict__ ol)
{
  const int tid = threadIdx.x;
  const int row = blockIdx.x * 4 + (tid >> 6);
  const int lane = tid & 63;
  const size_t idx = (size_t)row * Nn + lane;
  float val = o[idx];
  float mean = wave_sum(val) * (1.f / Nn);
  float d = val - mean;
  float var = wave_sum(d * d) * (1.f / Nn);
  float rs = rsqrtf(var + 1e-5f);
  int c = (row & (Hn - 1)) * Nn + lane;
  float r = (d * rs * g[c] + b[c]) * gate[idx];
  unsigned short h = f2bf(r);
  oh[idx] = h; ol[idx] = f2bf(r - bf2f(h));
}

// token-shift mix -> bf16 split pair(s)
__global__ __launch_bounds__(256) void mixshift_kernel(
    const float* __restrict__ xin,
    const float* __restrict__ maaA, unsigned short* __restrict__ oAh,
    unsigned short* __restrict__ oAl,
    const float* __restrict__ maaB, unsigned short* __restrict__ oBh,
    unsigned short* __restrict__ oBl, size_t n4)
{
  const int C4 = Cn / 4;
  for (size_t i = (size_t)blockIdx.x * 256 + threadIdx.x; i < n4;
       i += (size_t)gridDim.x * 256) {
    int c4 = (int)(i & (C4 - 1));
    size_t bt = i >> 8;
    float4 cur = ((const float4*)xin)[i];
    float4 prev = make_float4(0.f, 0.f, 0.f, 0.f);
    if (bt % Tn) prev = ((const float4*)xin)[i - C4];
    float4 ma = ((const float4*)maaA)[c4];
    float4 r = make_float4(
        cur.x + (prev.x - cur.x) * ma.x, cur.y + (prev.y - cur.y) * ma.y,
        cur.z + (prev.z - cur.z) * ma.z, cur.w + (prev.w - cur.w) * ma.w);
    uint2 H, L;
    split_f4(r, H.x, H.y, L.x, L.y);
    *(uint2*)(oAh + i * 4) = H; *(uint2*)(oAl + i * 4) = L;
    if (maaB) {
      float4 mb = ((const float4*)maaB)[c4];
      float4 r2 = make_float4(
          cur.x + (prev.x - cur.x) * mb.x, cur.y + (prev.y - cur.y) * mb.y,
          cur.z + (prev.z - cur.z) * mb.z, cur.w + (prev.w - cur.w) * mb.w);
      split_f4(r2, H.x, H.y, L.x, L.y);
      *(uint2*)(oBh + i * 4) = H; *(uint2*)(oBl + i * 4) = L;
    }
  }
}

// ---------------- epilogue ----------------
template<int EPI>
DEVI float epi_apply(float v, int row, int col, int Nc,
                     const float* e1, const float* e2, const float* e3)
{
  if constexpr (EPI == EPI_NONE) { return v; }
  else if constexpr (EPI == EPI_TANH) { return tanhf(v); }
  else if constexpr (EPI == EPI_SILU) { return v / (1.f + expf(-v)); }
  else if constexpr (EPI == EPI_SIGMOID) { return 1.f / (1.f + expf(-v)); }
  else if constexpr (EPI == EPI_RELU2) { float r = fmaxf(v, 0.f); return r * r; }
  else if constexpr (EPI == EPI_EW) { return expf(v + e1[col]); }
  else if constexpr (EPI == EPI_RESID) { return v + e1[(size_t)row * Nc + col]; }
  else if constexpr (EPI == EPI_MA3) {
    size_t i = (size_t)row * Nc + col; return (v + e3[i]) * e1[i] + e2[i];
  } else { // EPI_MIX
    size_t i = (size_t)row * Nc + col;
    float cur = e1[i];
    float prev = (row % Tn) ? e1[i - Cn] : 0.f;
    return cur + (prev - cur) * (e2[col] + v);
  }
}

// ---------------- fp32 vector GEMM (MIX only, K=32), split-bf16 output ----------------
__global__ __launch_bounds__(256) void gemm_mix(
    const float* __restrict__ A, int ldA,
    const float* __restrict__ W, unsigned short* __restrict__ oh,
    unsigned short* __restrict__ ol, int Nc, int K,
    const float* e1, const float* e2)
{
  constexpr int BK = 16;
  __shared__ float As[BK][132];
  __shared__ float Bs[BK][128];
  const int tid = threadIdx.x;
  const int m0 = blockIdx.y * 128, n0 = blockIdx.x * 128;
  const int tx = tid & 15, ty = tid >> 4;
  const int am = tid >> 2, ak = (tid & 3) << 2;
  const int bn = (tid & 31) << 2, bk = tid >> 5;

  float acc[8][8];
  #pragma unroll
  for (int i = 0; i < 8; i++)
    #pragma unroll
    for (int j = 0; j < 8; j++) acc[i][j] = 0.f;

  for (int k0 = 0; k0 < K; k0 += BK) {
    float4 va = *(const float4*)(A + (size_t)(m0 + am) * ldA + k0 + ak);
    float4 vb = *(const float4*)(A + (size_t)(m0 + 64 + am) * ldA + k0 + ak);
    float4 w1 = *(const float4*)(W + (size_t)(k0 + bk) * Nc + n0 + bn);
    float4 w2 = *(const float4*)(W + (size_t)(k0 + bk + 8) * Nc + n0 + bn);
    As[ak + 0][am] = va.x; As[ak + 1][am] = va.y;
    As[ak + 2][am] = va.z; As[ak + 3][am] = va.w;
    As[ak + 0][64 + am] = vb.x; As[ak + 1][64 + am] = vb.y;
    As[ak + 2][64 + am] = vb.z; As[ak + 3][64 + am] = vb.w;
    *(float4*)&Bs[bk][bn] = w1;
    *(float4*)&Bs[bk + 8][bn] = w2;
    __syncthreads();
    #pragma unroll
    for (int kk = 0; kk < BK; kk++) {
      float4 a0 = *(const float4*)&As[kk][ty * 8];
      float4 a1 = *(const float4*)&As[kk][ty * 8 + 4];
      float4 b0 = *(const float4*)&Bs[kk][tx * 8];
      float4 b1 = *(const float4*)&Bs[kk][tx * 8 + 4];
      float av[8] = {a0.x, a0.y, a0.z, a0.w, a1.x, a1.y, a1.z, a1.w};
      float bv[8] = {b0.x, b0.y, b0.z, b0.w, b1.x, b1.y, b1.z, b1.w};
      #pragma unroll
      for (int i = 0; i < 8; i++)
        #pragma unroll
        for (int j = 0; j < 8; j++)
          acc[i][j] = fmaf(av[i], bv[j], acc[i][j]);
    }
    __syncthreads();
  }

  #pragma unroll
  for (int i = 0; i < 8; i++) {
    int row = m0 + ty * 8 + i;
    #pragma unroll
    for (int jq = 0; jq < 2; jq++) {
      int col = n0 + tx * 8 + jq * 4;
      float4 rv;
      rv.x = epi_apply<EPI_MIX>(acc[i][jq*4+0], row, col+0, Nc, e1, e2, nullptr);
      rv.y = epi_apply<EPI_MIX>(acc[i][jq*4+1], row, col+1, Nc, e1, e2, nullptr);
      rv.z = epi_apply<EPI_MIX>(acc[i][jq*4+2], row, col+2, Nc, e1, e2, nullptr);
      rv.w = epi_apply<EPI_MIX>(acc[i][jq*4+3], row, col+3, Nc, e1, e2, nullptr);
      uint2 H, L;
      split_f4(rv, H.x, H.y, L.x, L.y);
      size_t o = (size_t)row * Nc + col;
      *(uint2*)(oh + o) = H; *(uint2*)(ol + o) = L;
    }
  }
}

// ---------------- MFMA GEMM: all-bf16 operands (pre-split) ----------------
// out[M,Nc] = A[M,K] @ B^T[Nc,K], acc = Ah*Bh + Ah*Bl + Al*Bh.
template<int EPI, int OM>
__global__ __launch_bounds__(256) void gemm_bf16(
    const unsigned short* __restrict__ Ah, const unsigned short* __restrict__ Al, int ldA,
    const unsigned short* __restrict__ Bh, const unsigned short* __restrict__ Bl, int ldB,
    float* __restrict__ outf, unsigned short* __restrict__ oh,
    unsigned short* __restrict__ ol, int Nc, int K,
    const float* __restrict__ e1, const float* __restrict__ e2,
    const float* __restrict__ e3)
{
  __shared__ unsigned short Ash[128][40], Asl[128][40], Bsh[128][40], Bsl[128][40];
  const int tid = threadIdx.x;
  const int m0 = blockIdx.y * 128, n0 = blockIdx.x * 128;
  const int wid = tid >> 6, lane = tid & 63;
  const int wm = (wid >> 1) * 64, wn = (wid & 1) * 64;
  const int fr = lane & 15, fq = lane >> 4;
  const int sr = tid >> 1, sc = (tid & 1) * 16;
  const bool bok = (n0 + sr) < Nc;

  f32x4 acc[4][4] = {};

  for (int k0 = 0; k0 < K; k0 += 32) {
    const unsigned short* Ap = Ah + (size_t)(m0 + sr) * ldA + k0 + sc;
    const unsigned short* Aq = Al + (size_t)(m0 + sr) * ldA + k0 + sc;
    uint4 a0 = *(const uint4*)Ap, a1 = *(const uint4*)(Ap + 8);
    uint4 b0 = *(const uint4*)Aq, b1 = *(const uint4*)(Aq + 8);
    uint4 z; z.x = z.y = z.z = z.w = 0;
    uint4 w0 = z, w1 = z, u0 = z, u1 = z;
    if (bok) {
      const unsigned short* Bp = Bh + (size_t)(n0 + sr) * ldB + k0 + sc;
      const unsigned short* Bq = Bl + (size_t)(n0 + sr) * ldB + k0 + sc;
      w0 = *(const uint4*)Bp; w1 = *(const uint4*)(Bp + 8);
      u0 = *(const uint4*)Bq; u1 = *(const uint4*)(Bq + 8);
    }
    *(uint4*)&Ash[sr][sc] = a0; *(uint4*)&Ash[sr][sc + 8] = a1;
    *(uint4*)&Asl[sr][sc] = b0; *(uint4*)&Asl[sr][sc + 8] = b1;
    *(uint4*)&Bsh[sr][sc] = w0; *(uint4*)&Bsh[sr][sc + 8] = w1;
    *(uint4*)&Bsl[sr][sc] = u0; *(uint4*)&Bsl[sr][sc + 8] = u1;
    __syncthreads();

    s16x8 fah[4], fal[4], fbh[4], fbl[4];
    #pragma unroll
    for (int i = 0; i < 4; i++) {
      fah[i] = *(const s16x8*)&Ash[wm + i * 16 + fr][fq * 8];
      fal[i] = *(const s16x8*)&Asl[wm + i * 16 + fr][fq * 8];
      fbh[i] = *(const s16x8*)&Bsh[wn + i * 16 + fr][fq * 8];
      fbl[i] = *(const s16x8*)&Bsl[wn + i * 16 + fr][fq * 8];
    }
    #pragma unroll
    for (int i = 0; i < 4; i++)
      #pragma unroll
      for (int j = 0; j < 4; j++) {
        acc[i][j] = __builtin_amdgcn_mfma_f32_16x16x32_bf16(fah[i], fbh[j], acc[i][j], 0, 0, 0);
        acc[i][j] = __builtin_amdgcn_mfma_f32_16x16x32_bf16(fah[i], fbl[j], acc[i][j], 0, 0, 0);
        acc[i][j] = __builtin_amdgcn_mfma_f32_16x16x32_bf16(fal[i], fbh[j], acc[i][j], 0, 0, 0);
      }
    __syncthreads();
  }

  #pragma unroll
  for (int i = 0; i < 4; i++)
    #pragma unroll
    for (int j = 0; j < 4; j++) {
      int col = n0 + wn + j * 16 + fr;
      if (col < Nc) {
        #pragma unroll
        for (int q = 0; q < 4; q++) {
          int row = m0 + wm + i * 16 + fq * 4 + q;
          float r = epi_apply<EPI>(acc[i][j][q], row, col, Nc, e1, e2, e3);
          size_t idx = (size_t)row * Nc + col;
          if constexpr (OM == OM_F32) {
            outf[idx] = r;
          } else {
            unsigned short h = f2bf(r);
            oh[idx] = h; ol[idx] = f2bf(r - bf2f(h));
          }
        }
      }
    }
}

// ---------------- chunked WKV6 scan ----------------
// grid: Bc*16*2 blocks (bh x m-half). 256 threads. chunk L=64.
__global__ __launch_bounds__(256) void wkv_chunk(
    const float* __restrict__ r_g, const float* __restrict__ k_g,
    const float* __restrict__ v_g, const float* __restrict__ ew_g,
    const float* __restrict__ u_g, float* __restrict__ o,
    float* __restrict__ Sf)
{
  __shared__ float Rm[64][68], Km[64][68], Wc[64][68], Pm[64][68], KT[64][68];
  __shared__ float Vh[64][36], Sh[64][36];
  __shared__ float U[64], Dg[64][4];

  const int bx = blockIdx.x;
  const int half = bx & 1, bh = bx >> 1;
  const int b = bh >> 4, h = bh & 15;
  const int mh = half * 32;
  const int tid = threadIdx.x;
  const int lt = tid >> 2, lq = tid & 3;
  const int ty = tid >> 4, tx = tid & 15;

  if (tid < 64) U[tid] = u_g[h * 64 + tid];
  for (int i = tid; i < 64 * 36; i += 256) (&Sh[0][0])[i] = 0.f;
  __syncthreads();

  const size_t base = (size_t)b * Tn * Cn + h * 64;

  for (int c = 0; c < Tn / 64; ++c) {
    const size_t rbase = base + (size_t)(c * 64 + lt) * Cn;
    float rr[16], kk[16], ww[16];
    #pragma unroll
    for (int j = 0; j < 4; j++) {
      float4 rv = *(const float4*)(r_g + rbase + lq * 16 + j * 4);
      float4 kv = *(const float4*)(k_g + rbase + lq * 16 + j * 4);
      float4 wv = *(const float4*)(ew_g + rbase + lq * 16 + j * 4);
      rr[j*4+0]=rv.x; rr[j*4+1]=rv.y; rr[j*4+2]=rv.z; rr[j*4+3]=rv.w;
      kk[j*4+0]=kv.x; kk[j*4+1]=kv.y; kk[j*4+2]=kv.z; kk[j*4+3]=kv.w;
      ww[j*4+0]=wv.x; ww[j*4+1]=wv.y; ww[j*4+2]=wv.z; ww[j*4+3]=wv.w;
      *(float4*)&Wc[lt][lq * 16 + j * 4] = wv;
    }
    #pragma unroll
    for (int j = 0; j < 2; j++)
      *(float4*)&Vh[lt][lq * 8 + j * 4] =
          *(const float4*)(v_g + rbase + mh + lq * 8 + j * 4);
    __syncthreads();

    // inclusive cumsum over t (Hillis-Steele)
    for (int s = 1; s < 64; s <<= 1) {
      float tmp[16];
      #pragma unroll
      for (int j = 0; j < 16; j++)
        tmp[j] = (lt >= s) ? Wc[lt - s][lq * 16 + j] : 0.f;
      __syncthreads();
      #pragma unroll
      for (int j = 0; j < 16; j++) Wc[lt][lq * 16 + j] += tmp[j];
      __syncthreads();
    }

    // transform: r~ = r*exp(-(ci-ew)); k~ = k*exp(ci); k^ = k*exp(ci-cend)
    float dgp = 0.f;
    #pragma unroll
    for (int j = 0; j < 16; j++) {
      int n = lq * 16 + j;
      float ci = Wc[lt][n];
      float cend = Wc[63][n];
      Rm[lt][n] = rr[j] * expf(-(ci - ww[j]));
      Km[lt][n] = kk[j] * expf(ci);
      KT[n][lt] = kk[j] * expf(ci - cend);
      dgp += rr[j] * U[n] * kk[j];
    }
    Dg[lt][lq] = dgp;
    __syncthreads();

    // P[t][tau] = r~_t . k~_tau  (mask: tau>t -> 0; tau==t -> sum r*u*k)
    {
      float pa[4][4] = {};
      for (int n = 0; n < 64; n += 4) {
        float4 ra[4], kb[4];
        #pragma unroll
        for (int i = 0; i < 4; i++) ra[i] = *(const float4*)&Rm[ty * 4 + i][n];
        #pragma unroll
        for (int j = 0; j < 4; j++) kb[j] = *(const float4*)&Km[tx * 4 + j][n];
        #pragma unroll
        for (int i = 0; i < 4; i++)
          #pragma unroll
          for (int j = 0; j < 4; j++)
            pa[i][j] += ra[i].x * kb[j].x + ra[i].y * kb[j].y +
                        ra[i].z * kb[j].z + ra[i].w * kb[j].w;
      }
      #pragma unroll
      for (int i = 0; i < 4; i++) {
        int t = ty * 4 + i;
        #pragma unroll
        for (int j = 0; j < 4; j++) {
          int tau = tx * 4 + j;
          float pv = pa[i][j];
          if (tau > t) pv = 0.f;
          else if (tau == t) pv = Dg[t][0] + Dg[t][1] + Dg[t][2] + Dg[t][3];
          Pm[t][tau] = pv;
        }
      }
    }
    __syncthreads();

    // O = P @ Vh + Rm @ Sh   (t-block ty*4, m-block tx*2)
    {
      float oa[4][2] = {};
      for (int tau = 0; tau < 64; tau += 4) {
        float4 p[4]; float2 vv[4];
        #pragma unroll
        for (int i = 0; i < 4; i++) p[i] = *(const float4*)&Pm[ty * 4 + i][tau];
        #pragma unroll
        for (int l = 0; l < 4; l++) vv[l] = *(const float2*)&Vh[tau + l][tx * 2];
        #pragma unroll
        for (int i = 0; i < 4; i++) {
          oa[i][0] += p[i].x*vv[0].x + p[i].y*vv[1].x + p[i].z*vv[2].x + p[i].w*vv[3].x;
          oa[i][1] += p[i].x*vv[0].y + p[i].y*vv[1].y + p[i].z*vv[2].y + p[i].w*vv[3].y;
        }
      }
      for (int n = 0; n < 64; n += 4) {
        float4 ra[4]; float2 sv[4];
        #pragma unroll
        for (int i = 0; i < 4; i++) ra[i] = *(const float4*)&Rm[ty * 4 + i][n];
        #pragma unroll
        for (int l = 0; l < 4; l++) sv[l] = *(const float2*)&Sh[n + l][tx * 2];
        #pragma unroll
        for (int i = 0; i < 4; i++) {
          oa[i][0] += ra[i].x*sv[0].x + ra[i].y*sv[1].x + ra[i].z*sv[2].x + ra[i].w*sv[3].x;
          oa[i][1] += ra[i].x*sv[0].y + ra[i].y*sv[1].y + ra[i].z*sv[2].y + ra[i].w*sv[3].y;
        }
      }
      #pragma unroll
      for (int i = 0; i < 4; i++) {
        float2 st; st.x = oa[i][0]; st.y = oa[i][1];
        *(float2*)(o + base + (size_t)(c * 64 + ty * 4 + i) * Cn + mh + tx * 2) = st;
      }
    }
    __syncthreads();

    // S = diag(exp(-cend)) S + KT @ Vh   (n-block ty*4, m-block tx*2)
    {
      float sa[4][2] = {};
      for (int t = 0; t < 64; t += 4) {
        float4 kc[4]; float2 vv[4];
        #pragma unroll
        for (int i = 0; i < 4; i++) kc[i] = *(const float4*)&KT[ty * 4 + i][t];
        #pragma unroll
        for (int l = 0; l < 4; l++) vv[l] = *(const float2*)&Vh[t + l][tx * 2];
        #pragma unroll
        for (int i = 0; i < 4; i++) {
          sa[i][0] += kc[i].x*vv[0].x + kc[i].y*vv[1].x + kc[i].z*vv[2].x + kc[i].w*vv[3].x;
          sa[i][1] += kc[i].x*vv[0].y + kc[i].y*vv[1].y + kc[i].z*vv[2].y + kc[i].w*vv[3].y;
        }
      }
      #pragma unroll
      for (int i = 0; i < 4; i++) {
        int n = ty * 4 + i;
        float dec = expf(-Wc[63][n]);
        Sh[n][tx*2+0] = dec * Sh[n][tx*2+0] + sa[i][0];
        Sh[n][tx*2+1] = dec * Sh[n][tx*2+1] + sa[i][1];
      }
    }
    __syncthreads();
  }

  #pragma unroll
  for (int i = 0; i < 4; i++) {
    int n = ty * 4 + i;
    size_t so = ((size_t)(b * Hn + h)) * 4096 + (size_t)n * 64 + mh + tx * 2;
    Sf[so] = Sh[n][tx * 2]; Sf[so + 1] = Sh[n][tx * 2 + 1];
  }
}

// ---------------- launchers ----------------
typedef unsigned short us;
static void launch_b16(hipStream_t st, int epi, int om,
                       const us* Ah, const us* Al, int ldA,
                       const us* Bh, const us* Bl, int ldB,
                       float* outf, us* oh, us* ol,
                       int M, int Nc, int K,
                       const float* e1 = nullptr, const float* e2 = nullptr,
                       const float* e3 = nullptr)
{
  dim3 g((Nc + 127) / 128, M / 128), blk(256);
  #define GB(E, O) gemm_bf16<E, O><<<g, blk, 0, st>>>(Ah, Al, ldA, Bh, Bl, ldB, outf, oh, ol, Nc, K, e1, e2, e3)
  if (om == OM_F32) {
    switch (epi) {
      case EPI_NONE:    GB(EPI_NONE, OM_F32); break;
      case EPI_TANH:    GB(EPI_TANH, OM_F32); break;
      case EPI_SILU:    GB(EPI_SILU, OM_F32); break;
      case EPI_SIGMOID: GB(EPI_SIGMOID, OM_F32); break;
      case EPI_EW:      GB(EPI_EW, OM_F32); break;
      case EPI_RESID:   GB(EPI_RESID, OM_F32); break;
      default:          GB(EPI_MA3, OM_F32); break;
    }
  } else {
    switch (epi) {
      case EPI_TANH:    GB(EPI_TANH, OM_SPLIT); break;
      default:          GB(EPI_RELU2, OM_SPLIT); break;
    }
  }
  #undef GB
}

extern "C" void kernel_launch(void* const* d_in, const int* in_sizes, int n_in,
                              void* d_out, int out_size, void* d_ws, size_t ws_size,
                              hipStream_t stream)
{
  const float* x        = (const float*)d_in[0];
  const float* ln0_g    = (const float*)d_in[1];
  const float* ln0_b    = (const float*)d_in[2];
  const float* ln1_g    = (const float*)d_in[3];
  const float* ln1_b    = (const float*)d_in[4];
  const float* ln2_g    = (const float*)d_in[5];
  const float* ln2_b    = (const float*)d_in[6];
  const float* lnx_g    = (const float*)d_in[7];
  const float* lnx_b    = (const float*)d_in[8];
  const float* maa_x    = (const float*)d_in[9];
  const float* maa[5]   = {(const float*)d_in[10], (const float*)d_in[11],
                           (const float*)d_in[12], (const float*)d_in[13],
                           (const float*)d_in[14]};            // w,k,v,r,g
  const float* tm_w1    = (const float*)d_in[15];
  const float* tm_w2    = (const float*)d_in[16];
  const float* tdecay   = (const float*)d_in[17];
  const float* td_w1    = (const float*)d_in[18];
  const float* td_w2    = (const float*)d_in[19];
  const float* faaaa    = (const float*)d_in[20];
  const float* Wr       = (const float*)d_in[21];
  const float* Wk       = (const float*)d_in[22];
  const float* Wv       = (const float*)d_in[23];
  const float* Wg       = (const float*)d_in[24];
  const float* Wo       = (const float*)d_in[25];
  const float* fmaa_k   = (const float*)d_in[26];
  const float* fmaa_r   = (const float*)d_in[27];
  const float* Wk_ffn   = (const float*)d_in[28];
  const float* Wv_ffn   = (const float*)d_in[29];
  const float* Wr_ffn   = (const float*)d_in[30];

  float* out = (float*)d_out;
  float* Sf  = out + BTC;

  // ---- WT area (bf16 transposed+split weights) ----
  const size_t M1 = 1024 * 1024, M35 = (size_t)1024 * 3584;
  us* wt = (us*)d_ws;
  size_t off = 0;
  auto ua = [&](size_t n) { us* p = wt + off; off += n; return p; };
  us *Tr_h = ua(M1),  *Tr_l = ua(M1);
  us *Tk_h = ua(M1),  *Tk_l = ua(M1);
  us *Tv_h = ua(M1),  *Tv_l = ua(M1);
  us *Tg_h = ua(M1),  *Tg_l = ua(M1);
  us *To_h = ua(M1),  *To_l = ua(M1);
  us *Trf_h = ua(M1), *Trf_l = ua(M1);
  us *Tkf_h = ua(M35), *Tkf_l = ua(M35);       // [3584][1024]
  us *Tvf_h = ua(M35), *Tvf_l = ua(M35);       // [1024][3584]
  us *Ttm1_h = ua((size_t)160 * 1024), *Ttm1_l = ua((size_t)160 * 1024);
  us *Ttd1_h = ua((size_t)64 * 1024),  *Ttd1_l = ua((size_t)64 * 1024);
  us *Ttd2_h = ua((size_t)1024 * 64),  *Ttd2_l = ua((size_t)1024 * 64);
  const size_t wt_bytes = off * 2;

  // chunk: 6 RC slots + lora(R*160 f32) + tdh pair(R*64*4B)
  int Bc = 0;
  for (int c = 8; c >= 1; c >>= 1) {
    size_t need = wt_bytes + (size_t)c * Tn * ((size_t)Cn * 6 + 224) * 4;
    if (need <= ws_size) { Bc = c; break; }
  }
  if (Bc == 0) {
    zero_kernel<<<2048, 256, 0, stream>>>(out, BTC + (size_t)Bn * Hn * Nn * Nn);
    return;
  }

  // transpose+split weights
  tsplit_kernel<<<dim3(16, 16), 256, 0, stream>>>(Wr, 1024, 1024, Tr_h, Tr_l);
  tsplit_kernel<<<dim3(16, 16), 256, 0, stream>>>(Wk, 1024, 1024, Tk_h, Tk_l);
  tsplit_kernel<<<dim3(16, 16), 256, 0, stream>>>(Wv, 1024, 1024, Tv_h, Tv_l);
  tsplit_kernel<<<dim3(16, 16), 256, 0, stream>>>(Wg, 1024, 1024, Tg_h, Tg_l);
  tsplit_kernel<<<dim3(16, 16), 256, 0, stream>>>(Wo, 1024, 1024, To_h, To_l);
  tsplit_kernel<<<dim3(16, 16), 256, 0, stream>>>(Wr_ffn, 1024, 1024, Trf_h, Trf_l);
  tsplit_kernel<<<dim3(56, 16), 256, 0, stream>>>(Wk_ffn, 1024, 3584, Tkf_h, Tkf_l);
  tsplit_kernel<<<dim3(16, 56), 256, 0, stream>>>(Wv_ffn, 3584, 1024, Tvf_h, Tvf_l);
  tsplit_kernel<<<dim3(3, 16), 256, 0, stream>>>(tm_w1, 1024, 160, Ttm1_h, Ttm1_l);
  tsplit_kernel<<<dim3(1, 16), 256, 0, stream>>>(td_w1, 1024, 64, Ttd1_h, Ttd1_l);
  tsplit_kernel<<<dim3(16, 1), 256, 0, stream>>>(td_w2, 64, 1024, Ttd2_h, Ttd2_l);

  const int    R  = Bc * Tn;
  const size_t RC = (size_t)R * Cn;
  float* S[6];
  S[0] = (float*)(wt + off);
  for (int i = 1; i < 6; i++) S[i] = S[i - 1] + RC;
  float* lora  = S[5] + RC;                    // R*160 f32
  us*    tdh_h = (us*)(lora + (size_t)R * 160);
  us*    tdh_l = tdh_h + (size_t)R * 64;

  for (int b0 = 0; b0 < Bn; b0 += Bc) {
    const size_t r0C = (size_t)b0 * Tn * Cn;
    const float* xc  = x + r0C;
    float*       x01 = out + r0C;
    float*       Sfc = Sf + (size_t)b0 * Hn * Nn * Nn;

    // pair views of slots (each RC-f32 slot == RC-bf16 hi + RC-bf16 lo)
    auto PH = [&](int i) { return (us*)S[i]; };
    auto PL = [&](int i) { return (us*)S[i] + RC; };

    // ---- time mix ----
    ln01_kernel<<<R, 256, 0, stream>>>(xc, ln0_g, ln0_b, ln1_g, ln1_b, x01, S[0]);
    // xxx pair -> S3
    mixshift_kernel<<<2048, 256, 0, stream>>>(S[0], maa_x, PH(3), PL(3),
                                              nullptr, nullptr, nullptr, RC / 4);
    // lora = tanh(xxx @ tm_w1) f32
    launch_b16(stream, EPI_TANH, OM_F32, PH(3), PL(3), 1024, Ttm1_h, Ttm1_l, 1024,
               lora, nullptr, nullptr, R, 160, 1024);
    dim3 gmix(1024 / 128, R / 128);
    // f=0 (w)
    gemm_mix<<<gmix, 256, 0, stream>>>(lora + 0 * 32, 160, tm_w2 + (size_t)0 * 32 * Cn,
                                       PH(1), PL(1), Cn, 32, S[0], maa[0]);
    launch_b16(stream, EPI_TANH, OM_SPLIT, PH(1), PL(1), 1024, Ttd1_h, Ttd1_l, 1024,
               nullptr, tdh_h, tdh_l, R, 64, 1024);
    launch_b16(stream, EPI_EW, OM_F32, tdh_h, tdh_l, 64, Ttd2_h, Ttd2_l, 64,
               S[2], nullptr, nullptr, R, 1024, 64, tdecay);
    // f=1 (k) -> S4
    gemm_mix<<<gmix, 256, 0, stream>>>(lora + 1 * 32, 160, tm_w2 + (size_t)1 * 32 * Cn,
                                       PH(1), PL(1), Cn, 32, S[0], maa[1]);
    launch_b16(stream, EPI_NONE, OM_F32, PH(1), PL(1), 1024, Tk_h, Tk_l, 1024,
               S[4], nullptr, nullptr, R, 1024, 1024);
    // f=2 (v) -> S5
    gemm_mix<<<gmix, 256, 0, stream>>>(lora + 2 * 32, 160, tm_w2 + (size_t)2 * 32 * Cn,
                                       PH(1), PL(1), Cn, 32, S[0], maa[2]);
    launch_b16(stream, EPI_NONE, OM_F32, PH(1), PL(1), 1024, Tv_h, Tv_l, 1024,
               S[5], nullptr, nullptr, R, 1024, 1024);
    // f=3 (r) -> S3 (xxx dead)
    gemm_mix<<<gmix, 256, 0, stream>>>(lora + 3 * 32, 160, tm_w2 + (size_t)3 * 32 * Cn,
                                       PH(1), PL(1), Cn, 32, S[0], maa[3]);
    launch_b16(stream, EPI_NONE, OM_F32, PH(1), PL(1), 1024, Tr_h, Tr_l, 1024,
               S[3], nullptr, nullptr, R, 1024, 1024);
    // f=4 (g) -> gate S0 (xa dead after this mix)
    gemm_mix<<<gmix, 256, 0, stream>>>(lora + 4 * 32, 160, tm_w2 + (size_t)4 * 32 * Cn,
                                       PH(1), PL(1), Cn, 32, S[0], maa[4]);
    launch_b16(stream, EPI_SILU, OM_F32, PH(1), PL(1), 1024, Tg_h, Tg_l, 1024,
               S[0], nullptr, nullptr, R, 1024, 1024);
    // WKV: r=S3 k=S4 v=S5 ew=S2 -> o=S1, Sfc
    wkv_chunk<<<Bc * Hn * 2, 256, 0, stream>>>(S[3], S[4], S[5], S[2], faaaa,
                                               S[1], Sfc);
    // gn*gate -> pair S2
    gn_kernel<<<R * Hn / 4, 256, 0, stream>>>(S[1], lnx_g, lnx_b, S[0],
                                              PH(2), PL(2));
    // x1 = x0 + o@Wo
    launch_b16(stream, EPI_RESID, OM_F32, PH(2), PL(2), 1024, To_h, To_l, 1024,
               x01, nullptr, nullptr, R, 1024, 1024, x01);

    // ---- channel mix ----
    ln_kernel<<<R, 256, 0, stream>>>(x01, ln2_g, ln2_b, S[1]);
    mixshift_kernel<<<2048, 256, 0, stream>>>(S[1], fmaa_k, PH(3), PL(3),
                                              fmaa_r, PH(4), PL(4), RC / 4);
    // rf = sigmoid(xrf @ Wr_ffn) -> S5
    launch_b16(stream, EPI_SIGMOID, OM_F32, PH(4), PL(4), 1024, Trf_h, Trf_l, 1024,
               S[5], nullptr, nullptr, R, 1024, 1024);
    // kk halves (N-split 1792): pair at S0..S1.75
    us* kk_h = (us*)S[0];
    us* kk_l = kk_h + (size_t)R * 1792;
    // half 1
    launch_b16(stream, EPI_RELU2, OM_SPLIT, PH(3), PL(3), 1024,
               Tkf_h, Tkf_l, 1024, nullptr, kk_h, kk_l, R, 1792, 1024);
    launch_b16(stream, EPI_NONE, OM_F32, kk_h, kk_l, 1792,
               Tvf_h, Tvf_l, 3584, S[2], nullptr, nullptr, R, 1024, 1792);
    // half 2
    launch_b16(stream, EPI_RELU2, OM_SPLIT, PH(3), PL(3), 1024,
               Tkf_h + (size_t)1792 * 1024, Tkf_l + (size_t)1792 * 1024, 1024,
               nullptr, kk_h, kk_l, R, 1792, 1024);
    launch_b16(stream, EPI_MA3, OM_F32, kk_h, kk_l, 1792,
               Tvf_h + 1792, Tvf_l + 1792, 3584, x01, nullptr, nullptr,
               R, 1024, 1792, S[5], x01, S[2]);
  }
}